// Round 5
// baseline (58.502 us; speedup 1.0000x reference)
//
#include <hip/hip_runtime.h>

// Problem constants (from reference: img_feats (8, 2048, 256) fp32)
#define BATCH 8
#define SEQ   2048
#define DIM   256
#define TINV  10.0f   // 1 / TEMPERATURE
#define NEGW  10      // NEG_WINDOW

// GEMM tiling
#define BM 128
#define BN 128
#define BK 64
#define NTILE (SEQ / BM)                  // 16
#define NPAIR (NTILE * (NTILE + 1) / 2)   // 136 (ti <= tj)

typedef float f32x4  __attribute__((ext_vector_type(4)));
typedef short bf16x8 __attribute__((ext_vector_type(8)));

// float -> bf16 (round-to-nearest-even), bf16 bits -> float
__device__ __forceinline__ unsigned short f2b(float f) {
  union { float f; unsigned u; } v; v.f = f;
  unsigned r = v.u + 0x7fffu + ((v.u >> 16) & 1u);
  return (unsigned short)(r >> 16);
}
__device__ __forceinline__ float b2f(unsigned short u) {
  union { unsigned u; float f; } v; v.u = ((unsigned)u) << 16;
  return v.f;
}

// ---------------------------------------------------------------------------
// Kernel 1: L2-normalize rows (fp32 in) -> bf16 normalized rows in workspace.
// Also zero-inits negsum[B][S] + loss accumulator + ticket (blocks 0..64).
// ---------------------------------------------------------------------------
__global__ void normalize_bf16_kernel(const float* __restrict__ x,
                                      unsigned short* __restrict__ xb,
                                      float* __restrict__ zero_region) {
  if (blockIdx.x < 64) {
    zero_region[blockIdx.x * 256 + threadIdx.x] = 0.f;   // negsum
  } else if (blockIdx.x == 64 && threadIdx.x < 16) {
    zero_region[16384 + threadIdx.x] = 0.f;              // loss, ticket, pad
  }
  int row  = blockIdx.x * 4 + (threadIdx.x >> 6);
  int lane = threadIdx.x & 63;
  const float4 v = reinterpret_cast<const float4*>(x + (size_t)row * DIM)[lane];
  float ss = v.x * v.x + v.y * v.y + v.z * v.z + v.w * v.w;
#pragma unroll
  for (int off = 32; off; off >>= 1) ss += __shfl_xor(ss, off, 64);
  float rn = 1.0f / fmaxf(sqrtf(ss), 1e-12f);
  ushort4 o;
  o.x = f2b(v.x * rn); o.y = f2b(v.y * rn);
  o.z = f2b(v.z * rn); o.w = f2b(v.w * rn);
  reinterpret_cast<ushort4*>(xb + (size_t)row * DIM)[lane] = o;
}

// ---------------------------------------------------------------------------
// Kernel 2: per-batch Gram tiles (ti<=tj, symmetry), bf16 MFMA 16x16x32.
// Round-5: ALL FOUR K-step tiles staged up front into 4 LDS buffers
// (128 KB, 1 block/CU) via global_load_lds w=16 with pre-swizzled global
// source; per K-step consume gated by counted s_waitcnt vmcnt(N) + raw
// s_barrier. Buffers written once / read once -> no WAR barriers, and
// loads for later K-steps stay in flight under earlier MFMA (the per-step
// __syncthreads() of round 4 drained vmcnt(0) and serialized the prefetch).
// Diag blocks stage A into both A and B buffers so vmcnt counts stay
// wave-uniform.
// ---------------------------------------------------------------------------
__device__ __forceinline__ void stage8(const unsigned short* __restrict__ G,
                                       unsigned short* dst_wave_uniform,
                                       int rowbase, int rl, int p, int kt) {
  // one global_load_lds: 64 lanes x 16B = 8 rows x 128B, linear LDS dest.
  int row = rowbase + rl;
  const unsigned short* src =
      G + (size_t)row * DIM + kt * BK + ((p ^ (row & 7)) << 3);
  __builtin_amdgcn_global_load_lds(
      (const __attribute__((address_space(1))) void*)src,
      (__attribute__((address_space(3))) void*)dst_wave_uniform, 16, 0, 0);
}

__global__ __launch_bounds__(256, 1)
void sim_negsum_kernel(const unsigned short* __restrict__ xb,
                       float* __restrict__ negsum,
                       float* __restrict__ sp_out) {
  const int b = blockIdx.y;
  int ti = 0, rem = blockIdx.x;
  while (rem >= NTILE - ti) { rem -= NTILE - ti; ti++; }
  const int tj = ti + rem;
  const bool diag = (ti == tj);
  const int s0 = ti * BM, t0 = tj * BN;

  __shared__ unsigned short Asm4[4][BM * BK];   // 4 x 16 KB
  __shared__ unsigned short Bsm4[4][BM * BK];   // 4 x 16 KB

  const unsigned short* Ag = xb + (size_t)b * SEQ * DIM + (size_t)s0 * DIM;
  const unsigned short* Bg = diag ? Ag
      : xb + (size_t)b * SEQ * DIM + (size_t)t0 * DIM;

  const int tid  = threadIdx.x;
  const int wid  = tid >> 6;
  const int lane = tid & 63;
  const int wm   = wid >> 1;       // wave row strip (0..1)
  const int wn   = wid & 1;        // wave col strip (0..1)
  const int kg   = lane >> 4;      // k-group 0..3
  const int cl   = lane & 15;
  const int rl   = lane >> 3;      // staging: row-in-group 0..7
  const int p    = lane & 7;       // staging: 16B slot 0..7

  f32x4 acc[4][4];
#pragma unroll
  for (int m = 0; m < 4; ++m)
#pragma unroll
    for (int n = 0; n < 4; ++n)
      acc[m][n] = (f32x4){0.f, 0.f, 0.f, 0.f};

  // ---- issue ALL staging loads up front (8 per K-step per wave) ----
  // Issue order kt-major => after vmcnt(32-8*(kt+1)), buffer kt is complete.
#pragma unroll
  for (int kt = 0; kt < 4; ++kt) {
#pragma unroll
    for (int it = 0; it < 4; ++it) {
      int rowbase = wid * 32 + it * 8;
      stage8(Ag, &Asm4[kt][rowbase * BK], rowbase, rl, p, kt);
      stage8(Bg, &Bsm4[kt][rowbase * BK], rowbase, rl, p, kt);
    }
  }

#define CONSUME(KT)                                                           \
  do {                                                                        \
    const char* Acur = (const char*)&Asm4[KT][0];                             \
    const char* Bcur = (const char*)&Bsm4[KT][0];                             \
    _Pragma("unroll")                                                         \
    for (int kk = 0; kk < BK / 32; ++kk) {                                    \
      bf16x8 af[4], bfr[4];                                                   \
      _Pragma("unroll")                                                       \
      for (int m = 0; m < 4; ++m) {                                           \
        int r = wm * 64 + m * 16 + cl;                                        \
        int slot = kk * 4 + kg;                                               \
        af[m] = *reinterpret_cast<const bf16x8*>(                             \
            Acur + r * 128 + ((slot ^ (r & 7)) << 4));                        \
      }                                                                       \
      _Pragma("unroll")                                                       \
      for (int n = 0; n < 4; ++n) {                                           \
        int r = wn * 64 + n * 16 + cl;                                        \
        int slot = kk * 4 + kg;                                               \
        bfr[n] = *reinterpret_cast<const bf16x8*>(                            \
            Bcur + r * 128 + ((slot ^ (r & 7)) << 4));                        \
      }                                                                       \
      _Pragma("unroll")                                                       \
      for (int m = 0; m < 4; ++m)                                             \
        _Pragma("unroll")                                                     \
        for (int n = 0; n < 4; ++n)                                           \
          acc[m][n] = __builtin_amdgcn_mfma_f32_16x16x32_bf16(                \
              af[m], bfr[n], acc[m][n], 0, 0, 0);                             \
    }                                                                         \
  } while (0)

#define SYNC_VM(VM)                                                           \
  asm volatile("s_waitcnt vmcnt(" #VM ")" ::: "memory");                      \
  __builtin_amdgcn_s_barrier();                                               \
  asm volatile("" ::: "memory");

  SYNC_VM(24) CONSUME(0);
  SYNC_VM(16) CONSUME(1);
  SYNC_VM(8)  CONSUME(2);
  SYNC_VM(0)  CONSUME(3);
#undef CONSUME
#undef SYNC_VM

  // ---- epilogue: exp + mask + row/col partial sums + sp extraction ----
  // C/D layout (HW-verified): col = lane&15, row = (lane>>4)*4 + reg
  float rowpart[4][4];
  float colpart[4];
#pragma unroll
  for (int m = 0; m < 4; ++m)
#pragma unroll
    for (int r = 0; r < 4; ++r) rowpart[m][r] = 0.f;
#pragma unroll
  for (int n = 0; n < 4; ++n) colpart[n] = 0.f;

#pragma unroll
  for (int m = 0; m < 4; ++m) {
#pragma unroll
    for (int n = 0; n < 4; ++n) {
#pragma unroll
      for (int r = 0; r < 4; ++r) {
        int srow = s0 + wm * 64 + m * 16 + (kg << 2) + r;
        int tcol = t0 + wn * 64 + n * 16 + cl;
        int diff = tcol - srow;
        int d = diff < 0 ? -diff : diff;
        float e = (d >= NEGW) ? __expf(acc[m][n][r] * TINV) : 0.f;
        rowpart[m][r] += e;
        colpart[n]    += e;
        if (diff == 1)   // positive pair (srow, srow+1): unique writer
          sp_out[(size_t)b * (SEQ - 1) + srow] = acc[m][n][r] * TINV;
      }
    }
  }

#pragma unroll
  for (int off = 1; off <= 8; off <<= 1)
#pragma unroll
    for (int m = 0; m < 4; ++m)
#pragma unroll
      for (int r = 0; r < 4; ++r)
        rowpart[m][r] += __shfl_xor(rowpart[m][r], off, 64);
  if (cl == 0) {
#pragma unroll
    for (int m = 0; m < 4; ++m)
#pragma unroll
      for (int r = 0; r < 4; ++r)
        atomicAdd(&negsum[(size_t)b * SEQ + s0 + wm * 64 + m * 16 + (kg << 2) + r],
                  rowpart[m][r]);
  }

  if (!diag) {
#pragma unroll
    for (int off = 16; off <= 32; off <<= 1)
#pragma unroll
      for (int n = 0; n < 4; ++n)
        colpart[n] += __shfl_xor(colpart[n], off, 64);
    if (lane < 16) {
#pragma unroll
      for (int n = 0; n < 4; ++n)
        atomicAdd(&negsum[(size_t)b * SEQ + t0 + wn * 64 + n * 16 + lane],
                  colpart[n]);
    }
  }
}

// ---------------------------------------------------------------------------
// Kernel 3: positive-pair loss from precomputed sp + FUSED finalize via
// last-block ticket (round-5: saves one dispatch). Every block also computes
// n_valid redundantly (cheap, data-independent); the block that takes the
// last ticket reads the final loss via atomicAdd(loss, 0) and writes out.
// ---------------------------------------------------------------------------
__device__ __forceinline__ int negcnt(int s) {
  int a = s - (NEGW - 1);      if (a < 0) a = 0;
  int b = SEQ - NEGW - s;      if (b < 0) b = 0;
  return a + b;
}

#define POSFIN_BLOCKS 64

__global__ __launch_bounds__(256)
void pos_fin_kernel(const float* __restrict__ sp,
                    const float* __restrict__ negsum,
                    float* __restrict__ loss,
                    unsigned int* __restrict__ ticket,
                    float* __restrict__ out) {
  __shared__ float red[4];
  __shared__ int   nvr[4];
  const int NP = BATCH * (SEQ - 1);
  int pidx = blockIdx.x * 256 + threadIdx.x;
  float term = 0.f;
  if (pidx < NP) {
    int b = pidx / (SEQ - 1), s = pidx % (SEQ - 1);
    float spv = sp[pidx];
    float e = __expf(spv);
    if (negcnt(s) > 0)     term += logf(e + negsum[(size_t)b * SEQ + s])     - spv;
    if (negcnt(s + 1) > 0) term += logf(e + negsum[(size_t)b * SEQ + s + 1]) - spv;
  }
  // n_valid (per-anchor positive counts over valid anchors), generic form
  int cnt = 0;
#pragma unroll
  for (int s = threadIdx.x; s < SEQ; s += 256)
    if (negcnt(s) > 0) cnt += (s > 0) + (s < SEQ - 1);

#pragma unroll
  for (int off = 32; off; off >>= 1) {
    term += __shfl_xor(term, off, 64);
    cnt  += __shfl_xor(cnt,  off, 64);
  }
  if ((threadIdx.x & 63) == 0) {
    red[threadIdx.x >> 6] = term;
    nvr[threadIdx.x >> 6] = cnt;
  }
  __syncthreads();
  if (threadIdx.x == 0) {
    atomicAdd(loss, red[0] + red[1] + red[2] + red[3]);
    long long nv = (long long)BATCH * (nvr[0] + nvr[1] + nvr[2] + nvr[3]);
    __threadfence();
    unsigned int old = atomicAdd(ticket, 1u);
    if (old == POSFIN_BLOCKS - 1) {
      float total = atomicAdd(loss, 0.0f);   // device-scope read of final sum
      out[0] = (nv > 0) ? total / (float)nv : 0.0f;
    }
  }
}

// ---------------------------------------------------------------------------
// Launch. Workspace layout (~8.6 MB):
//   [0, 8388608)              xb: bf16 normalized feats
//   [8388608, +65536)         negsum: fp32 [B][S]        (zeroed by k1)
//   [8454144, +4)             loss accumulator           (zeroed by k1)
//   [8454148, +4)             ticket                     (zeroed by k1)
//   [8454208, +65504)         sp: fp32 [B][S-1]          (fully overwritten)
// ---------------------------------------------------------------------------
extern "C" void kernel_launch(void* const* d_in, const int* in_sizes, int n_in,
                              void* d_out, int out_size, void* d_ws, size_t ws_size,
                              hipStream_t stream) {
  const float* x = (const float*)d_in[0];
  unsigned short* xb = (unsigned short*)d_ws;
  const size_t XB_BYTES = (size_t)BATCH * SEQ * DIM * 2;   // 8388608
  const size_t NS_BYTES = (size_t)BATCH * SEQ * 4;         // 65536
  float* negsum        = (float*)((char*)d_ws + XB_BYTES);
  float* loss          = (float*)((char*)d_ws + XB_BYTES + NS_BYTES);
  unsigned int* ticket = (unsigned int*)((char*)d_ws + XB_BYTES + NS_BYTES + 4);
  float* sp            = (float*)((char*)d_ws + XB_BYTES + NS_BYTES + 64);

  normalize_bf16_kernel<<<(BATCH * SEQ) / 4, 256, 0, stream>>>(x, xb, negsum);

  dim3 g2(NPAIR, BATCH);
  sim_negsum_kernel<<<g2, 256, 0, stream>>>(xb, negsum, sp);

  pos_fin_kernel<<<POSFIN_BLOCKS, 256, 0, stream>>>(sp, negsum, loss, ticket,
                                                    (float*)d_out);
}